// Round 12
// baseline (516.832 us; speedup 1.0000x reference)
//
#include <hip/hip_runtime.h>

typedef _Float16 f16;

#define NN 100000
#define NE 3200000
#define OVCAP 65536

#define BINSZ 64
#define NBIN ((NN + BINSZ - 1) / BINSZ)   // 1563 bins of 64 nodes
#define MAXPB 4096                         // max entries per bin (= cap)
#define SCAT_BLOCKS 512                    // scatter blocks (chunk ~6250 edges)

struct OvEnt { int dst; int src; float ew; int pad; };

// ================= bin pipeline =================

__global__ void k_zero(int* __restrict__ bincnt, int* __restrict__ ovcnt, int n) {
    int i = blockIdx.x * 256 + threadIdx.x;
    if (i < n) bincnt[i] = 0;
    if (i == 0) *ovcnt = 0;
}

// Two-pass LDS-histogram scatter. Pass 1: per-block histogram over 1563 bins
// (LDS atomics). Reserve: ONE global atomicAdd per nonzero bin per block.
// Pass 2: re-read chunk (L2-hot) and write entries; a block's entries for one
// bin are CONTIGUOUS -> full-line writebacks.
__global__ __launch_bounds__(256) void k_binscatter(
    const int* __restrict__ src, const int* __restrict__ dst,
    const float* __restrict__ ew, int* __restrict__ bincnt,
    uint2* __restrict__ binbuf, int cap,
    OvEnt* __restrict__ ov, int* __restrict__ ovcnt, int e) {
    __shared__ int hist[NBIN];
    int t = threadIdx.x;
    int chunk = (e + gridDim.x - 1) / gridDim.x;
    int beg = blockIdx.x * chunk;
    int end = beg + chunk; if (end > e) end = e;
    for (int j = t; j < NBIN; j += 256) hist[j] = 0;
    __syncthreads();
    // pass 1: histogram (dst only)
    for (int i = beg + t; i < end; i += 256)
        atomicAdd(&hist[dst[i] >> 6], 1);
    __syncthreads();
    // reserve global ranges; hist[bin] becomes the block's running cursor
    for (int j = t; j < NBIN; j += 256) {
        int c = hist[j];
        hist[j] = (c > 0) ? atomicAdd(&bincnt[j], c) : 0;
    }
    __syncthreads();
    // pass 2: scatter (chunk is L2-hot from pass 1)
    for (int i = beg + t; i < end; i += 256) {
        int s = src[i], d = dst[i];
        float w = ew[i];
        int bin = d >> 6;
        int pos = atomicAdd(&hist[bin], 1);
        if (pos < cap) {
            // pack: src in bits 0..16 (100000 < 2^17), dst&63 in bits 17..22
            unsigned key = (unsigned)s | ((unsigned)(d & 63) << 17);
            binbuf[(size_t)bin * cap + pos] = make_uint2(key, __float_as_uint(w));
        } else {
            int op = atomicAdd(ovcnt, 1);
            if (op < OVCAP) { OvEnt t2; t2.dst = d; t2.src = s; t2.ew = w; t2.pad = 0; ov[op] = t2; }
        }
    }
}

// Per-bin weighted degree -> dinv. Breaks the cross-bin dinv[src] dependency
// so the fused sort+gather can run without a global sorted-CSR round trip.
__global__ __launch_bounds__(256) void k_deg2(
    const int* __restrict__ bincnt, const uint2* __restrict__ binbuf, int cap,
    const OvEnt* __restrict__ ov, const int* __restrict__ ovcnt,
    float* __restrict__ dinv, int n) {
    __shared__ float sdeg[BINSZ];
    int bin = blockIdx.x, t = threadIdx.x;
    if (t < BINSZ) sdeg[t] = 0.f;
    __syncthreads();
    int cnt = bincnt[bin];
    int bc = cnt < cap ? cnt : cap;
    const uint2* base = binbuf + (size_t)bin * cap;
    for (int i = t; i < bc; i += 256) {
        uint2 v = base[i];
        atomicAdd(&sdeg[(v.x >> 17) & 63u], __uint_as_float(v.y));
    }
    if (cnt > cap) {
        int on = *ovcnt; if (on > OVCAP) on = OVCAP;
        for (int j = t; j < on; j += 256) {
            OvEnt e2 = ov[j];
            if ((e2.dst >> 6) == bin) atomicAdd(&sdeg[e2.dst & 63], e2.ew);
        }
    }
    __syncthreads();
    if (t < BINSZ) {
        int g = bin * BINSZ + t;
        if (g < n) dinv[g] = rsqrtf(1.0f + sdeg[t]);  // +1 = self loop
    }
}

// Fused per-bin counting sort (LDS only) + gather + bias/leakyrelu/LayerNorm.
// 512-thread blocks (8 waves/bin): 33.5 KB LDS -> 4 blocks/CU x 8 waves =
// 32 waves/CU (100% theoretical; r10's 4-wave blocks gave only 16). Entries
// in registers (8/thread); gather inner loop = proven 16-deep shfl MLP.
// h is fp16: halves the dominant L2-miss traffic (372 MB of h-row fetches).
__global__ __launch_bounds__(512) void k_sortgather(
    const f16* __restrict__ h, const float* __restrict__ dinv,
    const int* __restrict__ bincnt, const uint2* __restrict__ binbuf, int cap,
    const OvEnt* __restrict__ ov, const int* __restrict__ ovcnt,
    const float* __restrict__ bias, const float* __restrict__ gamma,
    const float* __restrict__ beta, float* __restrict__ out, int n) {
    __shared__ uint2 sbuf[MAXPB];          // 32 KB
    __shared__ float sd[BINSZ];
    __shared__ int hcnt[BINSZ];
    __shared__ int hoff[BINSZ];
    __shared__ int noff[BINSZ];
    int bin = blockIdx.x, t = threadIdx.x;
    int lane = t & 63, wid = t >> 6;

    if (t < BINSZ) {
        hcnt[t] = 0;
        int g = bin * BINSZ + t;
        sd[t] = (g < n) ? dinv[g] : 0.f;
    }
    __syncthreads();
    int cnt = bincnt[bin];
    int bc = cnt < cap ? cnt : cap;
    const uint2* base = binbuf + (size_t)bin * cap;

    // load bin entries to registers (coalesced)
    uint2 ent[8];
    int ne = 0;
#pragma unroll
    for (int p = 0; p < 8; p++) {
        int idx = t + p * 512;
        if (idx < bc) { ent[p] = base[idx]; ne = p + 1; }
    }
    // per-node histogram
#pragma unroll
    for (int p = 0; p < 8; p++)
        if (p < ne) atomicAdd(&hcnt[(int)((ent[p].x >> 17) & 63u)], 1);
    __syncthreads();
    // exclusive prefix (wave 0)
    if (t < 64) {
        int v = hcnt[t], inc = v;
#pragma unroll
        for (int o2 = 1; o2 < 64; o2 <<= 1) {
            int u = __shfl_up(inc, o2, 64);
            if (t >= o2) inc += u;
        }
        int excl = inc - v;
        hoff[t] = excl;
        noff[t] = excl;
    }
    __syncthreads();
    // permute into LDS (counting sort; no global write-back)
#pragma unroll
    for (int p = 0; p < 8; p++) {
        if (p < ne) {
            int dl = (int)((ent[p].x >> 17) & 63u);
            int pos = atomicAdd(&hoff[dl], 1);
            sbuf[pos] = ent[p];
        }
    }
    __syncthreads();

    // ===== gather phase: wave wid owns nodes dl = wid, wid+8, ... =====
    int sov = (cnt > cap);
    float bi = bias[lane], ga = gamma[lane], be = beta[lane];
    for (int dl = wid; dl < BINSZ; dl += 8) {
        int g = bin * BINSZ + dl;
        if (g >= n) break;
        float di = sd[dl];
        float acc = (float)h[(size_t)g * 64 + lane] * di * di;  // self loop
        int start = noff[dl], c0 = hcnt[dl];
        for (int j = 0; j < c0; j += 64) {
            int c = c0 - j; if (c > 64) c = 64;
            int s = 0; float w = 0.f;
            if (lane < c) {
                uint2 v = sbuf[start + j + lane];
                s = (int)(v.x & 0x1FFFFu);
                w = __uint_as_float(v.y) * dinv[s] * di;
            }
            int i2 = 0;
            for (; i2 + 16 <= c; i2 += 16) {
                float hv[16], wv[16];
#pragma unroll
                for (int q = 0; q < 16; q++) {
                    int si = __shfl(s, i2 + q, 64);
                    wv[q] = __shfl(w, i2 + q, 64);
                    hv[q] = (float)h[(size_t)si * 64 + lane];
                }
#pragma unroll
                for (int q = 0; q < 16; q++) acc += hv[q] * wv[q];
            }
            if (i2 < c) {
                float hv[16], wv[16];
                int rem = c - i2;
#pragma unroll
                for (int q = 0; q < 16; q++) {
                    if (q < rem) {
                        int si = __shfl(s, i2 + q, 64);
                        wv[q] = __shfl(w, i2 + q, 64);
                        hv[q] = (float)h[(size_t)si * 64 + lane];
                    } else { wv[q] = 0.f; hv[q] = 0.f; }
                }
#pragma unroll
                for (int q = 0; q < 16; q++) acc += hv[q] * wv[q];
            }
        }
        if (sov) {
            int on = *ovcnt; if (on > OVCAP) on = OVCAP;
            for (int j2 = 0; j2 < on; j2++) {
                OvEnt e2 = ov[j2];
                if (e2.dst == g)
                    acc += (float)h[(size_t)e2.src * 64 + lane] * dinv[e2.src] * e2.ew * di;
            }
        }
        float y = acc + bi;
        y = (y >= 0.f) ? y : 0.01f * y;
        float sum = y;
#pragma unroll
        for (int o = 32; o > 0; o >>= 1) sum += __shfl_xor(sum, o, 64);
        float mu = sum * (1.0f / 64.0f);
        float d = y - mu;
        float v = d * d;
#pragma unroll
        for (int o = 32; o > 0; o >>= 1) v += __shfl_xor(v, o, 64);
        v *= (1.0f / 64.0f);
        out[(size_t)g * 64 + lane] = d * rsqrtf(v + 1e-5f) * ga + be;
    }
}

// ================= GEMM: h[N,64] = x[N,256] @ W[256,64], fp16 output ======
// Occupancy-first tile: GR=64 rows, GK=32 k-slab -> LDS 17.4 KB (9 blk/CU),
// acc 4x4 -> ~80 VGPR (6 waves/SIMD), grid 1563 blocks.
#define GR 64
#define GKC 32
#define XS_STRIDE 36
__global__ __launch_bounds__(256) void k_gemm(const float* __restrict__ x,
                                              const float* __restrict__ W,
                                              f16* __restrict__ h, int n) {
    __shared__ float xs[GR][XS_STRIDE];   // 64*36*4 = 9216 B
    __shared__ float wsh[GKC][64];        // 32*64*4 = 8192 B
    int t = threadIdx.x;
    int tx = t & 15;        // col group: cols tx*4 .. tx*4+3
    int ty = t >> 4;        // row group: rows ty*4 .. ty*4+3
    int rbase = blockIdx.x * GR;
    float acc[4][4];
#pragma unroll
    for (int i = 0; i < 4; i++)
#pragma unroll
        for (int j = 0; j < 4; j++) acc[i][j] = 0.0f;

    for (int k0 = 0; k0 < 256; k0 += GKC) {
        // W tile: 32x64 = 512 float4, linear (wsh unpadded -> contiguous)
        const float4* wsrc = (const float4*)(W + k0 * 64);
        float4* wdst = (float4*)(&wsh[0][0]);
        wdst[t] = wsrc[t];
        wdst[t + 256] = wsrc[t + 256];
        // x tile: 64 rows x 32 k = 512 float4; 8 float4 per row
#pragma unroll
        for (int p = 0; p < 2; p++) {
            int f4 = p * 256 + t;
            int r = f4 >> 3;
            int kq = (f4 & 7) << 2;
            int row = rbase + r;
            float4 val = make_float4(0.f, 0.f, 0.f, 0.f);
            if (row < n) val = *(const float4*)(x + (size_t)row * 256 + k0 + kq);
            *(float4*)(&xs[r][kq]) = val;
        }
        __syncthreads();
        int r0 = ty * 4, c0 = tx * 4;
#pragma unroll
        for (int kk = 0; kk < GKC; kk += 4) {
            float4 wv[4];
#pragma unroll
            for (int m = 0; m < 4; m++) wv[m] = *(const float4*)(&wsh[kk + m][c0]);
#pragma unroll
            for (int i = 0; i < 4; i++) {
                float4 xv = *(const float4*)(&xs[r0 + i][kk]);
                acc[i][0] += xv.x * wv[0].x + xv.y * wv[1].x + xv.z * wv[2].x + xv.w * wv[3].x;
                acc[i][1] += xv.x * wv[0].y + xv.y * wv[1].y + xv.z * wv[2].y + xv.w * wv[3].y;
                acc[i][2] += xv.x * wv[0].z + xv.y * wv[1].z + xv.z * wv[2].z + xv.w * wv[3].z;
                acc[i][3] += xv.x * wv[0].w + xv.y * wv[1].w + xv.z * wv[2].w + xv.w * wv[3].w;
            }
        }
        __syncthreads();
    }
    int r0 = ty * 4, c0 = tx * 4;
#pragma unroll
    for (int i = 0; i < 4; i++) {
        int row = rbase + r0 + i;
        if (row < n) {
            union { f16 f[4]; uint2 u; } pk;
            pk.f[0] = (f16)acc[i][0];
            pk.f[1] = (f16)acc[i][1];
            pk.f[2] = (f16)acc[i][2];
            pk.f[3] = (f16)acc[i][3];
            *(uint2*)(h + (size_t)row * 64 + c0) = pk.u;
        }
    }
}

// ================= fallback pipeline (round-1, proven; fp16 h) ============

__global__ void k_init(float* __restrict__ deg, int* __restrict__ cnt, int n) {
    int i = blockIdx.x * 256 + threadIdx.x;
    if (i < n) { deg[i] = 1.0f; cnt[i] = 0; }
}

__global__ void k_deg(const int* __restrict__ dst, const float* __restrict__ ew,
                      float* __restrict__ deg, int* __restrict__ cnt, int e) {
    int i = blockIdx.x * 256 + threadIdx.x;
    if (i < e) {
        int d = dst[i];
        atomicAdd(&deg[d], ew[i]);
        atomicAdd(&cnt[d], 1);
    }
}

#define SCAN_T 256
#define SCAN_E 8
__global__ void k_scan_blocks(const int* __restrict__ cnt, int* __restrict__ off,
                              int* __restrict__ bsum, int n) {
    __shared__ int sdata[SCAN_T];
    int base = blockIdx.x * (SCAN_T * SCAN_E);
    int t = threadIdx.x;
    int v[SCAN_E];
    int local = 0;
    int idx0 = base + t * SCAN_E;
#pragma unroll
    for (int i = 0; i < SCAN_E; i++) {
        int idx = idx0 + i;
        int c = (idx < n) ? cnt[idx] : 0;
        v[i] = local;
        local += c;
    }
    sdata[t] = local;
    __syncthreads();
    for (int o = 1; o < SCAN_T; o <<= 1) {
        int x = 0;
        if (t >= o) x = sdata[t - o];
        __syncthreads();
        sdata[t] += x;
        __syncthreads();
    }
    int excl = sdata[t] - local;
#pragma unroll
    for (int i = 0; i < SCAN_E; i++) {
        int idx = idx0 + i;
        if (idx < n) off[idx] = excl + v[i];
    }
    if (t == SCAN_T - 1) bsum[blockIdx.x] = sdata[t];
}

__global__ void k_scan_bsums(int* __restrict__ bsum, int nb) {
    int t = threadIdx.x;
    int v = (t < nb) ? bsum[t] : 0;
    int orig = v;
#pragma unroll
    for (int o = 1; o < 64; o <<= 1) {
        int u = __shfl_up(v, o, 64);
        if (t >= o) v += u;
    }
    if (t < nb) bsum[t] = v - orig;
}

__global__ void k_finalize(int* __restrict__ off, const int* __restrict__ bsum,
                           int* __restrict__ cursor, float* __restrict__ deg,
                           int n, int total) {
    int i = blockIdx.x * 256 + threadIdx.x;
    if (i < n) {
        int o = off[i] + bsum[i >> 11];
        off[i] = o;
        cursor[i] = o;
        deg[i] = rsqrtf(deg[i]);
    }
    if (i == 0) off[n] = total;
}

__global__ void k_scatter(const int* __restrict__ src, const int* __restrict__ dst,
                          const float* __restrict__ ew, const float* __restrict__ dinv,
                          int* __restrict__ cursor, int* __restrict__ ssrc,
                          float* __restrict__ snorm, int e) {
    int i = blockIdx.x * 256 + threadIdx.x;
    if (i < e) {
        int s = src[i], d = dst[i];
        float nm = dinv[s] * ew[i] * dinv[d];
        int pos = atomicAdd(&cursor[d], 1);
        ssrc[pos] = s;
        snorm[pos] = nm;
    }
}

__global__ __launch_bounds__(256) void k_gather(
    const f16* __restrict__ h, const float* __restrict__ dinv,
    const int* __restrict__ off, const int* __restrict__ ssrc,
    const float* __restrict__ snorm, const float* __restrict__ bias,
    const float* __restrict__ gamma, const float* __restrict__ beta,
    float* __restrict__ out, int n) {
    int lane = threadIdx.x & 63;
    int wid = threadIdx.x >> 6;
    int node = blockIdx.x * 4 + wid;
    if (node >= n) return;
    float di = dinv[node];
    float acc = (float)h[(size_t)node * 64 + lane] * di * di;
    int beg = off[node], end = off[node + 1];
    for (int j = beg; j < end; j += 64) {
        int cnt = end - j;
        if (cnt > 64) cnt = 64;
        int s = 0;
        float w = 0.f;
        if (lane < cnt) { s = ssrc[j + lane]; w = snorm[j + lane]; }
        for (int i2 = 0; i2 < cnt; i2++) {
            int si = __shfl(s, i2, 64);
            float wi = __shfl(w, i2, 64);
            acc += (float)h[(size_t)si * 64 + lane] * wi;
        }
    }
    float y = acc + bias[lane];
    y = (y >= 0.f) ? y : 0.01f * y;
    float sum = y;
#pragma unroll
    for (int o = 32; o > 0; o >>= 1) sum += __shfl_xor(sum, o, 64);
    float mu = sum * (1.0f / 64.0f);
    float d = y - mu;
    float v = d * d;
#pragma unroll
    for (int o = 32; o > 0; o >>= 1) v += __shfl_xor(v, o, 64);
    v *= (1.0f / 64.0f);
    out[(size_t)node * 64 + lane] = d * rsqrtf(v + 1e-5f) * gamma[lane] + beta[lane];
}

// ================= launch =================

extern "C" void kernel_launch(void* const* d_in, const int* in_sizes, int n_in,
                              void* d_out, int out_size, void* d_ws, size_t ws_size,
                              hipStream_t stream) {
    const float* x = (const float*)d_in[0];
    const int* ei = (const int*)d_in[1];
    const float* ew = (const float*)d_in[2];
    const float* W = (const float*)d_in[3];
    const float* b = (const float*)d_in[4];
    const float* gamma = (const float*)d_in[5];
    const float* beta = (const float*)d_in[6];
    float* out = (float*)d_out;

    const int n = NN, e = NE;
    const int* src = ei;
    const int* dst = ei + e;

    char* ws = (char*)d_ws;
    size_t o = 0;
    auto alloc = [&](size_t bytes) -> char* {
        char* r = ws + o;
        o = (o + bytes + 255) & ~(size_t)255;
        return r;
    };
    auto pad = [](size_t bytes) -> size_t { return (bytes + 255) & ~(size_t)255; };

    int nb_n = (n + 255) / 256;
    int nb_e = (e + 255) / 256;
    int nb_gemm = (n + GR - 1) / GR;

    // bin-path fixed allocations
    size_t fixed = 0;
    fixed += pad((size_t)NBIN * 4);                   // bincnt
    fixed += 256;                                      // ovcnt
    fixed += pad((size_t)OVCAP * 16);                  // ov
    fixed += pad((size_t)n * 4);                       // dinv
    fixed += pad((size_t)n * 64 * 2);                  // h (fp16)

    // bin load ~ 2048 +- 45; cap 4096 is >40 sigma, 3072 is >20 sigma
    int cap = 0;
    if (ws_size >= fixed + pad((size_t)NBIN * 4096 * 8) + 8192) cap = 4096;
    else if (ws_size >= fixed + pad((size_t)NBIN * 3072 * 8) + 8192) cap = 3072;

    if (cap > 0) {
        int* bincnt = (int*)alloc((size_t)NBIN * 4);
        int* ovcnt = (int*)alloc(4);
        OvEnt* ov = (OvEnt*)alloc((size_t)OVCAP * 16);
        float* dinv = (float*)alloc((size_t)n * 4);
        f16* h = (f16*)alloc((size_t)n * 64 * 2);
        uint2* binbuf = (uint2*)alloc((size_t)NBIN * cap * 8);

        int nb_z = (NBIN + 255) / 256;
        k_zero<<<nb_z, 256, 0, stream>>>(bincnt, ovcnt, NBIN);
        k_binscatter<<<SCAT_BLOCKS, 256, 0, stream>>>(src, dst, ew, bincnt, binbuf, cap,
                                                      ov, ovcnt, e);
        k_deg2<<<NBIN, 256, 0, stream>>>(bincnt, binbuf, cap, ov, ovcnt, dinv, n);
        k_gemm<<<nb_gemm, 256, 0, stream>>>(x, W, h, n);
        k_sortgather<<<NBIN, 512, 0, stream>>>(h, dinv, bincnt, binbuf, cap,
                                               ov, ovcnt, b, gamma, beta, out, n);
    } else {
        // fallback: round-1 pipeline (fp16 h)
        float* deg = (float*)alloc((size_t)n * 4);
        int* cnt = (int*)alloc((size_t)n * 4);
        int* off = (int*)alloc((size_t)(n + 1) * 4);
        int* cursor = (int*)alloc((size_t)n * 4);
        int* bsum = (int*)alloc(64 * 4);
        f16* h = (f16*)alloc((size_t)n * 64 * 2);
        int* ssrc = (int*)alloc((size_t)e * 4);
        float* snorm = (float*)alloc((size_t)e * 4);
        int nb_scan = (n + SCAN_T * SCAN_E - 1) / (SCAN_T * SCAN_E);
        int nb_w = (n + 3) / 4;

        k_init<<<nb_n, 256, 0, stream>>>(deg, cnt, n);
        k_deg<<<nb_e, 256, 0, stream>>>(dst, ew, deg, cnt, e);
        k_scan_blocks<<<nb_scan, SCAN_T, 0, stream>>>(cnt, off, bsum, n);
        k_scan_bsums<<<1, 64, 0, stream>>>(bsum, nb_scan);
        k_finalize<<<nb_n, 256, 0, stream>>>(off, bsum, cursor, deg, n, e);
        k_scatter<<<nb_e, 256, 0, stream>>>(src, dst, ew, deg, cursor, ssrc, snorm, e);
        k_gemm<<<nb_gemm, 256, 0, stream>>>(x, W, h, n);
        k_gather<<<nb_w, 256, 0, stream>>>(h, deg, off, ssrc, snorm, b, gamma, beta, out, n);
    }
}

// Round 13
// 472.016 us; speedup vs baseline: 1.0949x; 1.0949x over previous
//
#include <hip/hip_runtime.h>

#define NN 100000
#define NE 3200000
#define OVCAP 65536

#define BINSZ 64
#define NBIN ((NN + BINSZ - 1) / BINSZ)   // 1563 bins of 64 nodes
#define MAXPB 4096                         // max entries per bin (= cap)
#define SCAT_BLOCKS 512                    // scatter blocks (chunk ~6250 edges)

struct OvEnt { int dst; int src; float ew; int pad; };

// ================= bin pipeline =================

__global__ void k_zero(int* __restrict__ bincnt, int* __restrict__ ovcnt, int n) {
    int i = blockIdx.x * 256 + threadIdx.x;
    if (i < n) bincnt[i] = 0;
    if (i == 0) *ovcnt = 0;
}

// Two-pass LDS-histogram scatter. Pass 1: per-block histogram over 1563 bins
// (LDS atomics). Reserve: ONE global atomicAdd per nonzero bin per block.
// Pass 2: re-read chunk (L2-hot) and write entries; a block's entries for one
// bin are CONTIGUOUS -> full-line writebacks.
__global__ __launch_bounds__(256) void k_binscatter(
    const int* __restrict__ src, const int* __restrict__ dst,
    const float* __restrict__ ew, int* __restrict__ bincnt,
    uint2* __restrict__ binbuf, int cap,
    OvEnt* __restrict__ ov, int* __restrict__ ovcnt, int e) {
    __shared__ int hist[NBIN];
    int t = threadIdx.x;
    int chunk = (e + gridDim.x - 1) / gridDim.x;
    int beg = blockIdx.x * chunk;
    int end = beg + chunk; if (end > e) end = e;
    for (int j = t; j < NBIN; j += 256) hist[j] = 0;
    __syncthreads();
    // pass 1: histogram (dst only)
    for (int i = beg + t; i < end; i += 256)
        atomicAdd(&hist[dst[i] >> 6], 1);
    __syncthreads();
    // reserve global ranges; hist[bin] becomes the block's running cursor
    for (int j = t; j < NBIN; j += 256) {
        int c = hist[j];
        hist[j] = (c > 0) ? atomicAdd(&bincnt[j], c) : 0;
    }
    __syncthreads();
    // pass 2: scatter (chunk is L2-hot from pass 1)
    for (int i = beg + t; i < end; i += 256) {
        int s = src[i], d = dst[i];
        float w = ew[i];
        int bin = d >> 6;
        int pos = atomicAdd(&hist[bin], 1);
        if (pos < cap) {
            // pack: src in bits 0..16 (100000 < 2^17), dst&63 in bits 17..22
            unsigned key = (unsigned)s | ((unsigned)(d & 63) << 17);
            binbuf[(size_t)bin * cap + pos] = make_uint2(key, __float_as_uint(w));
        } else {
            int op = atomicAdd(ovcnt, 1);
            if (op < OVCAP) { OvEnt t2; t2.dst = d; t2.src = s; t2.ew = w; t2.pad = 0; ov[op] = t2; }
        }
    }
}

// Per-bin weighted degree -> dinv. Breaks the cross-bin dinv[src] dependency
// so the fused sort+gather can run without a global sorted-CSR round trip.
__global__ __launch_bounds__(256) void k_deg2(
    const int* __restrict__ bincnt, const uint2* __restrict__ binbuf, int cap,
    const OvEnt* __restrict__ ov, const int* __restrict__ ovcnt,
    float* __restrict__ dinv, int n) {
    __shared__ float sdeg[BINSZ];
    int bin = blockIdx.x, t = threadIdx.x;
    if (t < BINSZ) sdeg[t] = 0.f;
    __syncthreads();
    int cnt = bincnt[bin];
    int bc = cnt < cap ? cnt : cap;
    const uint2* base = binbuf + (size_t)bin * cap;
    for (int i = t; i < bc; i += 256) {
        uint2 v = base[i];
        atomicAdd(&sdeg[(v.x >> 17) & 63u], __uint_as_float(v.y));
    }
    if (cnt > cap) {
        int on = *ovcnt; if (on > OVCAP) on = OVCAP;
        for (int j = t; j < on; j += 256) {
            OvEnt e2 = ov[j];
            if ((e2.dst >> 6) == bin) atomicAdd(&sdeg[e2.dst & 63], e2.ew);
        }
    }
    __syncthreads();
    if (t < BINSZ) {
        int g = bin * BINSZ + t;
        if (g < n) dinv[g] = rsqrtf(1.0f + sdeg[t]);  // +1 = self loop
    }
}

// Fused per-bin counting sort (LDS only, no global write-back) + gather +
// bias/leakyrelu/LayerNorm. 512-thread blocks (8 waves/bin): 33.8 KB LDS ->
// 4 blocks/CU x 8 waves = 32 waves/CU resident (r10's 256-thread version had
// only 16 waves/CU -> latency-bound at 142 us). fp32 h (r12's fp16 defeated
// the compiler's 16-deep load batching: VGPR 44 vs 52, +35% time).
// Gather inner loop = proven 16-deep shfl-broadcast MLP.
__global__ __launch_bounds__(512) void k_sortgather(
    const float* __restrict__ h, const float* __restrict__ dinv,
    const int* __restrict__ bincnt, const uint2* __restrict__ binbuf, int cap,
    const OvEnt* __restrict__ ov, const int* __restrict__ ovcnt,
    const float* __restrict__ bias, const float* __restrict__ gamma,
    const float* __restrict__ beta, float* __restrict__ out, int n) {
    __shared__ uint2 sbuf[MAXPB];          // 32 KB
    __shared__ float sd[BINSZ];
    __shared__ int hcnt[BINSZ];
    __shared__ int hoff[BINSZ];
    __shared__ int noff[BINSZ];
    int bin = blockIdx.x, t = threadIdx.x;
    int lane = t & 63, wid = t >> 6;

    if (t < BINSZ) {
        hcnt[t] = 0;
        int g = bin * BINSZ + t;
        sd[t] = (g < n) ? dinv[g] : 0.f;
    }
    __syncthreads();
    int cnt = bincnt[bin];
    int bc = cnt < cap ? cnt : cap;
    const uint2* base = binbuf + (size_t)bin * cap;

    // load bin entries to registers (coalesced)
    uint2 ent[8];
    int ne = 0;
#pragma unroll
    for (int p = 0; p < 8; p++) {
        int idx = t + p * 512;
        if (idx < bc) { ent[p] = base[idx]; ne = p + 1; }
    }
    // per-node histogram
#pragma unroll
    for (int p = 0; p < 8; p++)
        if (p < ne) atomicAdd(&hcnt[(int)((ent[p].x >> 17) & 63u)], 1);
    __syncthreads();
    // exclusive prefix (wave 0)
    if (t < 64) {
        int v = hcnt[t], inc = v;
#pragma unroll
        for (int o2 = 1; o2 < 64; o2 <<= 1) {
            int u = __shfl_up(inc, o2, 64);
            if (t >= o2) inc += u;
        }
        int excl = inc - v;
        hoff[t] = excl;
        noff[t] = excl;
    }
    __syncthreads();
    // permute into LDS (counting sort; no global write-back)
#pragma unroll
    for (int p = 0; p < 8; p++) {
        if (p < ne) {
            int dl = (int)((ent[p].x >> 17) & 63u);
            int pos = atomicAdd(&hoff[dl], 1);
            sbuf[pos] = ent[p];
        }
    }
    __syncthreads();

    // ===== gather phase: wave wid owns nodes dl = wid, wid+8, ... =====
    int sov = (cnt > cap);
    float bi = bias[lane], ga = gamma[lane], be = beta[lane];
    for (int dl = wid; dl < BINSZ; dl += 8) {
        int g = bin * BINSZ + dl;
        if (g >= n) break;
        float di = sd[dl];
        float acc = h[(size_t)g * 64 + lane] * di * di;  // self loop, weight 1
        int start = noff[dl], c0 = hcnt[dl];
        for (int j = 0; j < c0; j += 64) {
            int c = c0 - j; if (c > 64) c = 64;
            int s = 0; float w = 0.f;
            if (lane < c) {
                uint2 v = sbuf[start + j + lane];
                s = (int)(v.x & 0x1FFFFu);
                w = __uint_as_float(v.y) * dinv[s] * di;
            }
            int i2 = 0;
            for (; i2 + 16 <= c; i2 += 16) {
                float hv[16], wv[16];
#pragma unroll
                for (int q = 0; q < 16; q++) {
                    int si = __shfl(s, i2 + q, 64);
                    wv[q] = __shfl(w, i2 + q, 64);
                    hv[q] = h[(size_t)si * 64 + lane];
                }
#pragma unroll
                for (int q = 0; q < 16; q++) acc += hv[q] * wv[q];
            }
            if (i2 < c) {
                float hv[16], wv[16];
                int rem = c - i2;
#pragma unroll
                for (int q = 0; q < 16; q++) {
                    if (q < rem) {
                        int si = __shfl(s, i2 + q, 64);
                        wv[q] = __shfl(w, i2 + q, 64);
                        hv[q] = h[(size_t)si * 64 + lane];
                    } else { wv[q] = 0.f; hv[q] = 0.f; }
                }
#pragma unroll
                for (int q = 0; q < 16; q++) acc += hv[q] * wv[q];
            }
        }
        if (sov) {
            int on = *ovcnt; if (on > OVCAP) on = OVCAP;
            for (int j2 = 0; j2 < on; j2++) {
                OvEnt e2 = ov[j2];
                if (e2.dst == g)
                    acc += h[(size_t)e2.src * 64 + lane] * dinv[e2.src] * e2.ew * di;
            }
        }
        float y = acc + bi;
        y = (y >= 0.f) ? y : 0.01f * y;
        float sum = y;
#pragma unroll
        for (int o = 32; o > 0; o >>= 1) sum += __shfl_xor(sum, o, 64);
        float mu = sum * (1.0f / 64.0f);
        float d = y - mu;
        float v = d * d;
#pragma unroll
        for (int o = 32; o > 0; o >>= 1) v += __shfl_xor(v, o, 64);
        v *= (1.0f / 64.0f);
        out[(size_t)g * 64 + lane] = d * rsqrtf(v + 1e-5f) * ga + be;
    }
}

// ================= GEMM: h[N,64] = x[N,256] @ W[256,64] =================
// Occupancy-first tile: GR=64 rows, GK=32 k-slab -> LDS 17.4 KB (9 blk/CU),
// acc 4x4 -> ~80 VGPR (6 waves/SIMD), grid 1563 blocks.
#define GR 64
#define GKC 32
#define XS_STRIDE 36
__global__ __launch_bounds__(256) void k_gemm(const float* __restrict__ x,
                                              const float* __restrict__ W,
                                              float* __restrict__ h, int n) {
    __shared__ float xs[GR][XS_STRIDE];   // 64*36*4 = 9216 B
    __shared__ float wsh[GKC][64];        // 32*64*4 = 8192 B
    int t = threadIdx.x;
    int tx = t & 15;        // col group: cols tx*4 .. tx*4+3
    int ty = t >> 4;        // row group: rows ty*4 .. ty*4+3
    int rbase = blockIdx.x * GR;
    float acc[4][4];
#pragma unroll
    for (int i = 0; i < 4; i++)
#pragma unroll
        for (int j = 0; j < 4; j++) acc[i][j] = 0.0f;

    for (int k0 = 0; k0 < 256; k0 += GKC) {
        // W tile: 32x64 = 512 float4, linear (wsh unpadded -> contiguous)
        const float4* wsrc = (const float4*)(W + k0 * 64);
        float4* wdst = (float4*)(&wsh[0][0]);
        wdst[t] = wsrc[t];
        wdst[t + 256] = wsrc[t + 256];
        // x tile: 64 rows x 32 k = 512 float4; 8 float4 per row
#pragma unroll
        for (int p = 0; p < 2; p++) {
            int f4 = p * 256 + t;
            int r = f4 >> 3;
            int kq = (f4 & 7) << 2;
            int row = rbase + r;
            float4 val = make_float4(0.f, 0.f, 0.f, 0.f);
            if (row < n) val = *(const float4*)(x + (size_t)row * 256 + k0 + kq);
            *(float4*)(&xs[r][kq]) = val;
        }
        __syncthreads();
        int r0 = ty * 4, c0 = tx * 4;
#pragma unroll
        for (int kk = 0; kk < GKC; kk += 4) {
            float4 wv[4];
#pragma unroll
            for (int m = 0; m < 4; m++) wv[m] = *(const float4*)(&wsh[kk + m][c0]);
#pragma unroll
            for (int i = 0; i < 4; i++) {
                float4 xv = *(const float4*)(&xs[r0 + i][kk]);
                acc[i][0] += xv.x * wv[0].x + xv.y * wv[1].x + xv.z * wv[2].x + xv.w * wv[3].x;
                acc[i][1] += xv.x * wv[0].y + xv.y * wv[1].y + xv.z * wv[2].y + xv.w * wv[3].y;
                acc[i][2] += xv.x * wv[0].z + xv.y * wv[1].z + xv.z * wv[2].z + xv.w * wv[3].z;
                acc[i][3] += xv.x * wv[0].w + xv.y * wv[1].w + xv.z * wv[2].w + xv.w * wv[3].w;
            }
        }
        __syncthreads();
    }
    int r0 = ty * 4, c0 = tx * 4;
#pragma unroll
    for (int i = 0; i < 4; i++) {
        int row = rbase + r0 + i;
        if (row < n) {
            float4 v = make_float4(acc[i][0], acc[i][1], acc[i][2], acc[i][3]);
            *(float4*)(h + (size_t)row * 64 + c0) = v;
        }
    }
}

// ================= fallback pipeline (round-1, proven) =================

__global__ void k_init(float* __restrict__ deg, int* __restrict__ cnt, int n) {
    int i = blockIdx.x * 256 + threadIdx.x;
    if (i < n) { deg[i] = 1.0f; cnt[i] = 0; }
}

__global__ void k_deg(const int* __restrict__ dst, const float* __restrict__ ew,
                      float* __restrict__ deg, int* __restrict__ cnt, int e) {
    int i = blockIdx.x * 256 + threadIdx.x;
    if (i < e) {
        int d = dst[i];
        atomicAdd(&deg[d], ew[i]);
        atomicAdd(&cnt[d], 1);
    }
}

#define SCAN_T 256
#define SCAN_E 8
__global__ void k_scan_blocks(const int* __restrict__ cnt, int* __restrict__ off,
                              int* __restrict__ bsum, int n) {
    __shared__ int sdata[SCAN_T];
    int base = blockIdx.x * (SCAN_T * SCAN_E);
    int t = threadIdx.x;
    int v[SCAN_E];
    int local = 0;
    int idx0 = base + t * SCAN_E;
#pragma unroll
    for (int i = 0; i < SCAN_E; i++) {
        int idx = idx0 + i;
        int c = (idx < n) ? cnt[idx] : 0;
        v[i] = local;
        local += c;
    }
    sdata[t] = local;
    __syncthreads();
    for (int o = 1; o < SCAN_T; o <<= 1) {
        int x = 0;
        if (t >= o) x = sdata[t - o];
        __syncthreads();
        sdata[t] += x;
        __syncthreads();
    }
    int excl = sdata[t] - local;
#pragma unroll
    for (int i = 0; i < SCAN_E; i++) {
        int idx = idx0 + i;
        if (idx < n) off[idx] = excl + v[i];
    }
    if (t == SCAN_T - 1) bsum[blockIdx.x] = sdata[t];
}

__global__ void k_scan_bsums(int* __restrict__ bsum, int nb) {
    int t = threadIdx.x;
    int v = (t < nb) ? bsum[t] : 0;
    int orig = v;
#pragma unroll
    for (int o = 1; o < 64; o <<= 1) {
        int u = __shfl_up(v, o, 64);
        if (t >= o) v += u;
    }
    if (t < nb) bsum[t] = v - orig;
}

__global__ void k_finalize(int* __restrict__ off, const int* __restrict__ bsum,
                           int* __restrict__ cursor, float* __restrict__ deg,
                           int n, int total) {
    int i = blockIdx.x * 256 + threadIdx.x;
    if (i < n) {
        int o = off[i] + bsum[i >> 11];
        off[i] = o;
        cursor[i] = o;
        deg[i] = rsqrtf(deg[i]);
    }
    if (i == 0) off[n] = total;
}

__global__ void k_scatter(const int* __restrict__ src, const int* __restrict__ dst,
                          const float* __restrict__ ew, const float* __restrict__ dinv,
                          int* __restrict__ cursor, int* __restrict__ ssrc,
                          float* __restrict__ snorm, int e) {
    int i = blockIdx.x * 256 + threadIdx.x;
    if (i < e) {
        int s = src[i], d = dst[i];
        float nm = dinv[s] * ew[i] * dinv[d];
        int pos = atomicAdd(&cursor[d], 1);
        ssrc[pos] = s;
        snorm[pos] = nm;
    }
}

__global__ __launch_bounds__(256) void k_gather(
    const float* __restrict__ h, const float* __restrict__ dinv,
    const int* __restrict__ off, const int* __restrict__ ssrc,
    const float* __restrict__ snorm, const float* __restrict__ bias,
    const float* __restrict__ gamma, const float* __restrict__ beta,
    float* __restrict__ out, int n) {
    int lane = threadIdx.x & 63;
    int wid = threadIdx.x >> 6;
    int node = blockIdx.x * 4 + wid;
    if (node >= n) return;
    float di = dinv[node];
    float acc = h[(size_t)node * 64 + lane] * di * di;
    int beg = off[node], end = off[node + 1];
    for (int j = beg; j < end; j += 64) {
        int cnt = end - j;
        if (cnt > 64) cnt = 64;
        int s = 0;
        float w = 0.f;
        if (lane < cnt) { s = ssrc[j + lane]; w = snorm[j + lane]; }
        for (int i2 = 0; i2 < cnt; i2++) {
            int si = __shfl(s, i2, 64);
            float wi = __shfl(w, i2, 64);
            acc += h[(size_t)si * 64 + lane] * wi;
        }
    }
    float y = acc + bias[lane];
    y = (y >= 0.f) ? y : 0.01f * y;
    float sum = y;
#pragma unroll
    for (int o = 32; o > 0; o >>= 1) sum += __shfl_xor(sum, o, 64);
    float mu = sum * (1.0f / 64.0f);
    float d = y - mu;
    float v = d * d;
#pragma unroll
    for (int o = 32; o > 0; o >>= 1) v += __shfl_xor(v, o, 64);
    v *= (1.0f / 64.0f);
    out[(size_t)node * 64 + lane] = d * rsqrtf(v + 1e-5f) * gamma[lane] + beta[lane];
}

// ================= launch =================

extern "C" void kernel_launch(void* const* d_in, const int* in_sizes, int n_in,
                              void* d_out, int out_size, void* d_ws, size_t ws_size,
                              hipStream_t stream) {
    const float* x = (const float*)d_in[0];
    const int* ei = (const int*)d_in[1];
    const float* ew = (const float*)d_in[2];
    const float* W = (const float*)d_in[3];
    const float* b = (const float*)d_in[4];
    const float* gamma = (const float*)d_in[5];
    const float* beta = (const float*)d_in[6];
    float* out = (float*)d_out;

    const int n = NN, e = NE;
    const int* src = ei;
    const int* dst = ei + e;

    char* ws = (char*)d_ws;
    size_t o = 0;
    auto alloc = [&](size_t bytes) -> char* {
        char* r = ws + o;
        o = (o + bytes + 255) & ~(size_t)255;
        return r;
    };
    auto pad = [](size_t bytes) -> size_t { return (bytes + 255) & ~(size_t)255; };

    int nb_n = (n + 255) / 256;
    int nb_e = (e + 255) / 256;
    int nb_gemm = (n + GR - 1) / GR;

    // bin-path fixed allocations
    size_t fixed = 0;
    fixed += pad((size_t)NBIN * 4);                   // bincnt
    fixed += 256;                                      // ovcnt
    fixed += pad((size_t)OVCAP * 16);                  // ov
    fixed += pad((size_t)n * 4);                       // dinv
    fixed += pad((size_t)n * 64 * 4);                  // h

    // bin load ~ 2048 +- 45; cap 4096 is >40 sigma, 3072 is >20 sigma
    int cap = 0;
    if (ws_size >= fixed + pad((size_t)NBIN * 4096 * 8) + 8192) cap = 4096;
    else if (ws_size >= fixed + pad((size_t)NBIN * 3072 * 8) + 8192) cap = 3072;

    if (cap > 0) {
        int* bincnt = (int*)alloc((size_t)NBIN * 4);
        int* ovcnt = (int*)alloc(4);
        OvEnt* ov = (OvEnt*)alloc((size_t)OVCAP * 16);
        float* dinv = (float*)alloc((size_t)n * 4);
        float* h = (float*)alloc((size_t)n * 64 * 4);
        uint2* binbuf = (uint2*)alloc((size_t)NBIN * cap * 8);

        int nb_z = (NBIN + 255) / 256;
        k_zero<<<nb_z, 256, 0, stream>>>(bincnt, ovcnt, NBIN);
        k_binscatter<<<SCAT_BLOCKS, 256, 0, stream>>>(src, dst, ew, bincnt, binbuf, cap,
                                                      ov, ovcnt, e);
        k_deg2<<<NBIN, 256, 0, stream>>>(bincnt, binbuf, cap, ov, ovcnt, dinv, n);
        k_gemm<<<nb_gemm, 256, 0, stream>>>(x, W, h, n);
        k_sortgather<<<NBIN, 512, 0, stream>>>(h, dinv, bincnt, binbuf, cap,
                                               ov, ovcnt, b, gamma, beta, out, n);
    } else {
        // fallback: round-1 pipeline
        float* deg = (float*)alloc((size_t)n * 4);
        int* cnt = (int*)alloc((size_t)n * 4);
        int* off = (int*)alloc((size_t)(n + 1) * 4);
        int* cursor = (int*)alloc((size_t)n * 4);
        int* bsum = (int*)alloc(64 * 4);
        float* h = (float*)alloc((size_t)n * 64 * 4);
        int* ssrc = (int*)alloc((size_t)e * 4);
        float* snorm = (float*)alloc((size_t)e * 4);
        int nb_scan = (n + SCAN_T * SCAN_E - 1) / (SCAN_T * SCAN_E);
        int nb_w = (n + 3) / 4;

        k_init<<<nb_n, 256, 0, stream>>>(deg, cnt, n);
        k_deg<<<nb_e, 256, 0, stream>>>(dst, ew, deg, cnt, e);
        k_scan_blocks<<<nb_scan, SCAN_T, 0, stream>>>(cnt, off, bsum, n);
        k_scan_bsums<<<1, 64, 0, stream>>>(bsum, nb_scan);
        k_finalize<<<nb_n, 256, 0, stream>>>(off, bsum, cursor, deg, n, e);
        k_scatter<<<nb_e, 256, 0, stream>>>(src, dst, ew, deg, cursor, ssrc, snorm, e);
        k_gemm<<<nb_gemm, 256, 0, stream>>>(x, W, h, n);
        k_gather<<<nb_w, 256, 0, stream>>>(h, deg, off, ssrc, snorm, b, gamma, beta, out, n);
    }
}

// Round 14
// 457.005 us; speedup vs baseline: 1.1309x; 1.0328x over previous
//
#include <hip/hip_runtime.h>

#define NN 100000
#define NE 3200000
#define OVCAP 65536

#define BINSZ 64
#define NBIN ((NN + BINSZ - 1) / BINSZ)   // 1563 bins of 64 nodes
#define MAXPB 4096                         // max entries per bin (= cap)
#define SCAT_BLOCKS 512                    // scatter blocks (chunk ~6250 edges)

// GEMM tile params (shared by fused + fallback)
#define GR 64
#define GKC 32
#define XS_STRIDE 36

struct OvEnt { int dst; int src; float ew; int pad; };

// ================= bin pipeline =================

__global__ void k_zero(int* __restrict__ bincnt, int* __restrict__ ovcnt, int n) {
    int i = blockIdx.x * 256 + threadIdx.x;
    if (i < n) bincnt[i] = 0;
    if (i == 0) *ovcnt = 0;
}

// Heterogeneous fused kernel: blocks [0, SCAT_BLOCKS) run the two-pass
// LDS-histogram edge scatter; blocks [SCAT_BLOCKS, +nb_gemm) run GEMM tiles.
// The two phases are independent (scatter: edge list -> binbuf; gemm: x,W -> h)
// and use complementary pipes (atomic/store vs VALU/LDS), so running them
// co-resident costs ~max instead of sum. Scatter blocks first so they start
// dispatching immediately. One 17.4 KB LDS overlay serves both roles.
__global__ __launch_bounds__(256) void k_gemm_scatter(
    const float* __restrict__ x, const float* __restrict__ W,
    float* __restrict__ h,
    const int* __restrict__ src, const int* __restrict__ dst,
    const float* __restrict__ ew, int* __restrict__ bincnt,
    uint2* __restrict__ binbuf, int cap,
    OvEnt* __restrict__ ov, int* __restrict__ ovcnt, int e, int n) {
    __shared__ char smem[17408];
    int t = threadIdx.x;

    if (blockIdx.x < SCAT_BLOCKS) {
        // ============ scatter role ============
        int* hist = (int*)smem;                      // NBIN ints = 6252 B
        int chunk = (e + SCAT_BLOCKS - 1) / SCAT_BLOCKS;
        int beg = blockIdx.x * chunk;
        int end = beg + chunk; if (end > e) end = e;
        for (int j = t; j < NBIN; j += 256) hist[j] = 0;
        __syncthreads();
        // pass 1: histogram (dst only)
        for (int i = beg + t; i < end; i += 256)
            atomicAdd(&hist[dst[i] >> 6], 1);
        __syncthreads();
        // reserve global ranges; hist[bin] becomes the block's running cursor
        for (int j = t; j < NBIN; j += 256) {
            int c = hist[j];
            hist[j] = (c > 0) ? atomicAdd(&bincnt[j], c) : 0;
        }
        __syncthreads();
        // pass 2: scatter (chunk is L2-hot from pass 1)
        for (int i = beg + t; i < end; i += 256) {
            int s = src[i], d = dst[i];
            float w = ew[i];
            int bin = d >> 6;
            int pos = atomicAdd(&hist[bin], 1);
            if (pos < cap) {
                // pack: src bits 0..16 (100000 < 2^17), dst&63 bits 17..22
                unsigned key = (unsigned)s | ((unsigned)(d & 63) << 17);
                binbuf[(size_t)bin * cap + pos] = make_uint2(key, __float_as_uint(w));
            } else {
                int op = atomicAdd(ovcnt, 1);
                if (op < OVCAP) { OvEnt t2; t2.dst = d; t2.src = s; t2.ew = w; t2.pad = 0; ov[op] = t2; }
            }
        }
    } else {
        // ============ gemm role: h[N,64] = x[N,256] @ W[256,64] ============
        float (*xs)[XS_STRIDE] = (float(*)[XS_STRIDE])smem;         // 9216 B
        float (*wsh)[64] = (float(*)[64])(smem + 9216);             // 8192 B
        int tx = t & 15;
        int ty = t >> 4;
        int rbase = (blockIdx.x - SCAT_BLOCKS) * GR;
        float acc[4][4];
#pragma unroll
        for (int i = 0; i < 4; i++)
#pragma unroll
            for (int j = 0; j < 4; j++) acc[i][j] = 0.0f;

        for (int k0 = 0; k0 < 256; k0 += GKC) {
            const float4* wsrc = (const float4*)(W + k0 * 64);
            float4* wdst = (float4*)(&wsh[0][0]);
            wdst[t] = wsrc[t];
            wdst[t + 256] = wsrc[t + 256];
#pragma unroll
            for (int p = 0; p < 2; p++) {
                int f4 = p * 256 + t;
                int r = f4 >> 3;
                int kq = (f4 & 7) << 2;
                int row = rbase + r;
                float4 val = make_float4(0.f, 0.f, 0.f, 0.f);
                if (row < n) val = *(const float4*)(x + (size_t)row * 256 + k0 + kq);
                *(float4*)(&xs[r][kq]) = val;
            }
            __syncthreads();
            int r0 = ty * 4, c0 = tx * 4;
#pragma unroll
            for (int kk = 0; kk < GKC; kk += 4) {
                float4 wv[4];
#pragma unroll
                for (int m = 0; m < 4; m++) wv[m] = *(const float4*)(&wsh[kk + m][c0]);
#pragma unroll
                for (int i = 0; i < 4; i++) {
                    float4 xv = *(const float4*)(&xs[r0 + i][kk]);
                    acc[i][0] += xv.x * wv[0].x + xv.y * wv[1].x + xv.z * wv[2].x + xv.w * wv[3].x;
                    acc[i][1] += xv.x * wv[0].y + xv.y * wv[1].y + xv.z * wv[2].y + xv.w * wv[3].y;
                    acc[i][2] += xv.x * wv[0].z + xv.y * wv[1].z + xv.z * wv[2].z + xv.w * wv[3].z;
                    acc[i][3] += xv.x * wv[0].w + xv.y * wv[1].w + xv.z * wv[2].w + xv.w * wv[3].w;
                }
            }
            __syncthreads();
        }
        int r0 = ty * 4, c0 = tx * 4;
#pragma unroll
        for (int i = 0; i < 4; i++) {
            int row = rbase + r0 + i;
            if (row < n) {
                float4 v = make_float4(acc[i][0], acc[i][1], acc[i][2], acc[i][3]);
                *(float4*)(h + (size_t)row * 64 + c0) = v;
            }
        }
    }
}

// Per-bin weighted degree -> dinv.
__global__ __launch_bounds__(256) void k_deg2(
    const int* __restrict__ bincnt, const uint2* __restrict__ binbuf, int cap,
    const OvEnt* __restrict__ ov, const int* __restrict__ ovcnt,
    float* __restrict__ dinv, int n) {
    __shared__ float sdeg[BINSZ];
    int bin = blockIdx.x, t = threadIdx.x;
    if (t < BINSZ) sdeg[t] = 0.f;
    __syncthreads();
    int cnt = bincnt[bin];
    int bc = cnt < cap ? cnt : cap;
    const uint2* base = binbuf + (size_t)bin * cap;
    for (int i = t; i < bc; i += 256) {
        uint2 v = base[i];
        atomicAdd(&sdeg[(v.x >> 17) & 63u], __uint_as_float(v.y));
    }
    if (cnt > cap) {
        int on = *ovcnt; if (on > OVCAP) on = OVCAP;
        for (int j = t; j < on; j += 256) {
            OvEnt e2 = ov[j];
            if ((e2.dst >> 6) == bin) atomicAdd(&sdeg[e2.dst & 63], e2.ew);
        }
    }
    __syncthreads();
    if (t < BINSZ) {
        int g = bin * BINSZ + t;
        if (g < n) dinv[g] = rsqrtf(1.0f + sdeg[t]);  // +1 = self loop
    }
}

// Fused per-bin counting sort (LDS only) + gather + bias/leakyrelu/LayerNorm.
// 512-thread blocks (8 waves/bin), fp32 h, 16-deep shfl-broadcast MLP.
__global__ __launch_bounds__(512) void k_sortgather(
    const float* __restrict__ h, const float* __restrict__ dinv,
    const int* __restrict__ bincnt, const uint2* __restrict__ binbuf, int cap,
    const OvEnt* __restrict__ ov, const int* __restrict__ ovcnt,
    const float* __restrict__ bias, const float* __restrict__ gamma,
    const float* __restrict__ beta, float* __restrict__ out, int n) {
    __shared__ uint2 sbuf[MAXPB];          // 32 KB
    __shared__ float sd[BINSZ];
    __shared__ int hcnt[BINSZ];
    __shared__ int hoff[BINSZ];
    __shared__ int noff[BINSZ];
    int bin = blockIdx.x, t = threadIdx.x;
    int lane = t & 63, wid = t >> 6;

    if (t < BINSZ) {
        hcnt[t] = 0;
        int g = bin * BINSZ + t;
        sd[t] = (g < n) ? dinv[g] : 0.f;
    }
    __syncthreads();
    int cnt = bincnt[bin];
    int bc = cnt < cap ? cnt : cap;
    const uint2* base = binbuf + (size_t)bin * cap;

    // load bin entries to registers (coalesced)
    uint2 ent[8];
    int ne = 0;
#pragma unroll
    for (int p = 0; p < 8; p++) {
        int idx = t + p * 512;
        if (idx < bc) { ent[p] = base[idx]; ne = p + 1; }
    }
    // per-node histogram
#pragma unroll
    for (int p = 0; p < 8; p++)
        if (p < ne) atomicAdd(&hcnt[(int)((ent[p].x >> 17) & 63u)], 1);
    __syncthreads();
    // exclusive prefix (wave 0)
    if (t < 64) {
        int v = hcnt[t], inc = v;
#pragma unroll
        for (int o2 = 1; o2 < 64; o2 <<= 1) {
            int u = __shfl_up(inc, o2, 64);
            if (t >= o2) inc += u;
        }
        int excl = inc - v;
        hoff[t] = excl;
        noff[t] = excl;
    }
    __syncthreads();
    // permute into LDS (counting sort; no global write-back)
#pragma unroll
    for (int p = 0; p < 8; p++) {
        if (p < ne) {
            int dl = (int)((ent[p].x >> 17) & 63u);
            int pos = atomicAdd(&hoff[dl], 1);
            sbuf[pos] = ent[p];
        }
    }
    __syncthreads();

    // ===== gather phase: wave wid owns nodes dl = wid, wid+8, ... =====
    int sov = (cnt > cap);
    float bi = bias[lane], ga = gamma[lane], be = beta[lane];
    for (int dl = wid; dl < BINSZ; dl += 8) {
        int g = bin * BINSZ + dl;
        if (g >= n) break;
        float di = sd[dl];
        float acc = h[(size_t)g * 64 + lane] * di * di;  // self loop, weight 1
        int start = noff[dl], c0 = hcnt[dl];
        for (int j = 0; j < c0; j += 64) {
            int c = c0 - j; if (c > 64) c = 64;
            int s = 0; float w = 0.f;
            if (lane < c) {
                uint2 v = sbuf[start + j + lane];
                s = (int)(v.x & 0x1FFFFu);
                w = __uint_as_float(v.y) * dinv[s] * di;
            }
            int i2 = 0;
            for (; i2 + 16 <= c; i2 += 16) {
                float hv[16], wv[16];
#pragma unroll
                for (int q = 0; q < 16; q++) {
                    int si = __shfl(s, i2 + q, 64);
                    wv[q] = __shfl(w, i2 + q, 64);
                    hv[q] = h[(size_t)si * 64 + lane];
                }
#pragma unroll
                for (int q = 0; q < 16; q++) acc += hv[q] * wv[q];
            }
            if (i2 < c) {
                float hv[16], wv[16];
                int rem = c - i2;
#pragma unroll
                for (int q = 0; q < 16; q++) {
                    if (q < rem) {
                        int si = __shfl(s, i2 + q, 64);
                        wv[q] = __shfl(w, i2 + q, 64);
                        hv[q] = h[(size_t)si * 64 + lane];
                    } else { wv[q] = 0.f; hv[q] = 0.f; }
                }
#pragma unroll
                for (int q = 0; q < 16; q++) acc += hv[q] * wv[q];
            }
        }
        if (sov) {
            int on = *ovcnt; if (on > OVCAP) on = OVCAP;
            for (int j2 = 0; j2 < on; j2++) {
                OvEnt e2 = ov[j2];
                if (e2.dst == g)
                    acc += h[(size_t)e2.src * 64 + lane] * dinv[e2.src] * e2.ew * di;
            }
        }
        float y = acc + bi;
        y = (y >= 0.f) ? y : 0.01f * y;
        float sum = y;
#pragma unroll
        for (int o = 32; o > 0; o >>= 1) sum += __shfl_xor(sum, o, 64);
        float mu = sum * (1.0f / 64.0f);
        float d = y - mu;
        float v = d * d;
#pragma unroll
        for (int o = 32; o > 0; o >>= 1) v += __shfl_xor(v, o, 64);
        v *= (1.0f / 64.0f);
        out[(size_t)g * 64 + lane] = d * rsqrtf(v + 1e-5f) * ga + be;
    }
}

// ================= standalone GEMM (fallback path) =================
__global__ __launch_bounds__(256) void k_gemm(const float* __restrict__ x,
                                              const float* __restrict__ W,
                                              float* __restrict__ h, int n) {
    __shared__ float xs[GR][XS_STRIDE];
    __shared__ float wsh[GKC][64];
    int t = threadIdx.x;
    int tx = t & 15;
    int ty = t >> 4;
    int rbase = blockIdx.x * GR;
    float acc[4][4];
#pragma unroll
    for (int i = 0; i < 4; i++)
#pragma unroll
        for (int j = 0; j < 4; j++) acc[i][j] = 0.0f;

    for (int k0 = 0; k0 < 256; k0 += GKC) {
        const float4* wsrc = (const float4*)(W + k0 * 64);
        float4* wdst = (float4*)(&wsh[0][0]);
        wdst[t] = wsrc[t];
        wdst[t + 256] = wsrc[t + 256];
#pragma unroll
        for (int p = 0; p < 2; p++) {
            int f4 = p * 256 + t;
            int r = f4 >> 3;
            int kq = (f4 & 7) << 2;
            int row = rbase + r;
            float4 val = make_float4(0.f, 0.f, 0.f, 0.f);
            if (row < n) val = *(const float4*)(x + (size_t)row * 256 + k0 + kq);
            *(float4*)(&xs[r][kq]) = val;
        }
        __syncthreads();
        int r0 = ty * 4, c0 = tx * 4;
#pragma unroll
        for (int kk = 0; kk < GKC; kk += 4) {
            float4 wv[4];
#pragma unroll
            for (int m = 0; m < 4; m++) wv[m] = *(const float4*)(&wsh[kk + m][c0]);
#pragma unroll
            for (int i = 0; i < 4; i++) {
                float4 xv = *(const float4*)(&xs[r0 + i][kk]);
                acc[i][0] += xv.x * wv[0].x + xv.y * wv[1].x + xv.z * wv[2].x + xv.w * wv[3].x;
                acc[i][1] += xv.x * wv[0].y + xv.y * wv[1].y + xv.z * wv[2].y + xv.w * wv[3].y;
                acc[i][2] += xv.x * wv[0].z + xv.y * wv[1].z + xv.z * wv[2].z + xv.w * wv[3].z;
                acc[i][3] += xv.x * wv[0].w + xv.y * wv[1].w + xv.z * wv[2].w + xv.w * wv[3].w;
            }
        }
        __syncthreads();
    }
    int r0 = ty * 4, c0 = tx * 4;
#pragma unroll
    for (int i = 0; i < 4; i++) {
        int row = rbase + r0 + i;
        if (row < n) {
            float4 v = make_float4(acc[i][0], acc[i][1], acc[i][2], acc[i][3]);
            *(float4*)(h + (size_t)row * 64 + c0) = v;
        }
    }
}

// ================= fallback pipeline (round-1, proven) =================

__global__ void k_init(float* __restrict__ deg, int* __restrict__ cnt, int n) {
    int i = blockIdx.x * 256 + threadIdx.x;
    if (i < n) { deg[i] = 1.0f; cnt[i] = 0; }
}

__global__ void k_deg(const int* __restrict__ dst, const float* __restrict__ ew,
                      float* __restrict__ deg, int* __restrict__ cnt, int e) {
    int i = blockIdx.x * 256 + threadIdx.x;
    if (i < e) {
        int d = dst[i];
        atomicAdd(&deg[d], ew[i]);
        atomicAdd(&cnt[d], 1);
    }
}

#define SCAN_T 256
#define SCAN_E 8
__global__ void k_scan_blocks(const int* __restrict__ cnt, int* __restrict__ off,
                              int* __restrict__ bsum, int n) {
    __shared__ int sdata[SCAN_T];
    int base = blockIdx.x * (SCAN_T * SCAN_E);
    int t = threadIdx.x;
    int v[SCAN_E];
    int local = 0;
    int idx0 = base + t * SCAN_E;
#pragma unroll
    for (int i = 0; i < SCAN_E; i++) {
        int idx = idx0 + i;
        int c = (idx < n) ? cnt[idx] : 0;
        v[i] = local;
        local += c;
    }
    sdata[t] = local;
    __syncthreads();
    for (int o = 1; o < SCAN_T; o <<= 1) {
        int x = 0;
        if (t >= o) x = sdata[t - o];
        __syncthreads();
        sdata[t] += x;
        __syncthreads();
    }
    int excl = sdata[t] - local;
#pragma unroll
    for (int i = 0; i < SCAN_E; i++) {
        int idx = idx0 + i;
        if (idx < n) off[idx] = excl + v[i];
    }
    if (t == SCAN_T - 1) bsum[blockIdx.x] = sdata[t];
}

__global__ void k_scan_bsums(int* __restrict__ bsum, int nb) {
    int t = threadIdx.x;
    int v = (t < nb) ? bsum[t] : 0;
    int orig = v;
#pragma unroll
    for (int o = 1; o < 64; o <<= 1) {
        int u = __shfl_up(v, o, 64);
        if (t >= o) v += u;
    }
    if (t < nb) bsum[t] = v - orig;
}

__global__ void k_finalize(int* __restrict__ off, const int* __restrict__ bsum,
                           int* __restrict__ cursor, float* __restrict__ deg,
                           int n, int total) {
    int i = blockIdx.x * 256 + threadIdx.x;
    if (i < n) {
        int o = off[i] + bsum[i >> 11];
        off[i] = o;
        cursor[i] = o;
        deg[i] = rsqrtf(deg[i]);
    }
    if (i == 0) off[n] = total;
}

__global__ void k_scatter(const int* __restrict__ src, const int* __restrict__ dst,
                          const float* __restrict__ ew, const float* __restrict__ dinv,
                          int* __restrict__ cursor, int* __restrict__ ssrc,
                          float* __restrict__ snorm, int e) {
    int i = blockIdx.x * 256 + threadIdx.x;
    if (i < e) {
        int s = src[i], d = dst[i];
        float nm = dinv[s] * ew[i] * dinv[d];
        int pos = atomicAdd(&cursor[d], 1);
        ssrc[pos] = s;
        snorm[pos] = nm;
    }
}

__global__ __launch_bounds__(256) void k_gather(
    const float* __restrict__ h, const float* __restrict__ dinv,
    const int* __restrict__ off, const int* __restrict__ ssrc,
    const float* __restrict__ snorm, const float* __restrict__ bias,
    const float* __restrict__ gamma, const float* __restrict__ beta,
    float* __restrict__ out, int n) {
    int lane = threadIdx.x & 63;
    int wid = threadIdx.x >> 6;
    int node = blockIdx.x * 4 + wid;
    if (node >= n) return;
    float di = dinv[node];
    float acc = h[(size_t)node * 64 + lane] * di * di;
    int beg = off[node], end = off[node + 1];
    for (int j = beg; j < end; j += 64) {
        int cnt = end - j;
        if (cnt > 64) cnt = 64;
        int s = 0;
        float w = 0.f;
        if (lane < cnt) { s = ssrc[j + lane]; w = snorm[j + lane]; }
        for (int i2 = 0; i2 < cnt; i2++) {
            int si = __shfl(s, i2, 64);
            float wi = __shfl(w, i2, 64);
            acc += h[(size_t)si * 64 + lane] * wi;
        }
    }
    float y = acc + bias[lane];
    y = (y >= 0.f) ? y : 0.01f * y;
    float sum = y;
#pragma unroll
    for (int o = 32; o > 0; o >>= 1) sum += __shfl_xor(sum, o, 64);
    float mu = sum * (1.0f / 64.0f);
    float d = y - mu;
    float v = d * d;
#pragma unroll
    for (int o = 32; o > 0; o >>= 1) v += __shfl_xor(v, o, 64);
    v *= (1.0f / 64.0f);
    out[(size_t)node * 64 + lane] = d * rsqrtf(v + 1e-5f) * gamma[lane] + beta[lane];
}

// ================= launch =================

extern "C" void kernel_launch(void* const* d_in, const int* in_sizes, int n_in,
                              void* d_out, int out_size, void* d_ws, size_t ws_size,
                              hipStream_t stream) {
    const float* x = (const float*)d_in[0];
    const int* ei = (const int*)d_in[1];
    const float* ew = (const float*)d_in[2];
    const float* W = (const float*)d_in[3];
    const float* b = (const float*)d_in[4];
    const float* gamma = (const float*)d_in[5];
    const float* beta = (const float*)d_in[6];
    float* out = (float*)d_out;

    const int n = NN, e = NE;
    const int* src = ei;
    const int* dst = ei + e;

    char* ws = (char*)d_ws;
    size_t o = 0;
    auto alloc = [&](size_t bytes) -> char* {
        char* r = ws + o;
        o = (o + bytes + 255) & ~(size_t)255;
        return r;
    };
    auto pad = [](size_t bytes) -> size_t { return (bytes + 255) & ~(size_t)255; };

    int nb_n = (n + 255) / 256;
    int nb_e = (e + 255) / 256;
    int nb_gemm = (n + GR - 1) / GR;

    // bin-path fixed allocations
    size_t fixed = 0;
    fixed += pad((size_t)NBIN * 4);                   // bincnt
    fixed += 256;                                      // ovcnt
    fixed += pad((size_t)OVCAP * 16);                  // ov
    fixed += pad((size_t)n * 4);                       // dinv
    fixed += pad((size_t)n * 64 * 4);                  // h

    // bin load ~ 2048 +- 45; cap 4096 is >40 sigma, 3072 is >20 sigma
    int cap = 0;
    if (ws_size >= fixed + pad((size_t)NBIN * 4096 * 8) + 8192) cap = 4096;
    else if (ws_size >= fixed + pad((size_t)NBIN * 3072 * 8) + 8192) cap = 3072;

    if (cap > 0) {
        int* bincnt = (int*)alloc((size_t)NBIN * 4);
        int* ovcnt = (int*)alloc(4);
        OvEnt* ov = (OvEnt*)alloc((size_t)OVCAP * 16);
        float* dinv = (float*)alloc((size_t)n * 4);
        float* h = (float*)alloc((size_t)n * 64 * 4);
        uint2* binbuf = (uint2*)alloc((size_t)NBIN * cap * 8);

        int nb_z = (NBIN + 255) / 256;
        k_zero<<<nb_z, 256, 0, stream>>>(bincnt, ovcnt, NBIN);
        k_gemm_scatter<<<SCAT_BLOCKS + nb_gemm, 256, 0, stream>>>(
            x, W, h, src, dst, ew, bincnt, binbuf, cap, ov, ovcnt, e, n);
        k_deg2<<<NBIN, 256, 0, stream>>>(bincnt, binbuf, cap, ov, ovcnt, dinv, n);
        k_sortgather<<<NBIN, 512, 0, stream>>>(h, dinv, bincnt, binbuf, cap,
                                               ov, ovcnt, b, gamma, beta, out, n);
    } else {
        // fallback: round-1 pipeline
        float* deg = (float*)alloc((size_t)n * 4);
        int* cnt = (int*)alloc((size_t)n * 4);
        int* off = (int*)alloc((size_t)(n + 1) * 4);
        int* cursor = (int*)alloc((size_t)n * 4);
        int* bsum = (int*)alloc(64 * 4);
        float* h = (float*)alloc((size_t)n * 64 * 4);
        int* ssrc = (int*)alloc((size_t)e * 4);
        float* snorm = (float*)alloc((size_t)e * 4);
        int nb_scan = (n + SCAN_T * SCAN_E - 1) / (SCAN_T * SCAN_E);
        int nb_w = (n + 3) / 4;

        k_init<<<nb_n, 256, 0, stream>>>(deg, cnt, n);
        k_deg<<<nb_e, 256, 0, stream>>>(dst, ew, deg, cnt, e);
        k_scan_blocks<<<nb_scan, SCAN_T, 0, stream>>>(cnt, off, bsum, n);
        k_scan_bsums<<<1, 64, 0, stream>>>(bsum, nb_scan);
        k_finalize<<<nb_n, 256, 0, stream>>>(off, bsum, cursor, deg, n, e);
        k_scatter<<<nb_e, 256, 0, stream>>>(src, dst, ew, deg, cursor, ssrc, snorm, e);
        k_gemm<<<nb_gemm, 256, 0, stream>>>(x, W, h, n);
        k_gather<<<nb_w, 256, 0, stream>>>(h, deg, off, ssrc, snorm, b, gamma, beta, out, n);
    }
}